// Round 5
// baseline (63.042 us; speedup 1.0000x reference)
//
#include <hip/hip_runtime.h>
#include <stdint.h>

typedef __bf16 bf16_t;
typedef __bf16 bf16x8 __attribute__((ext_vector_type(8)));
typedef float f32x16 __attribute__((ext_vector_type(16)));
typedef unsigned short ushort8 __attribute__((ext_vector_type(8)));

#define M_DIM 16384
#define N_DIM 1024
#define K_DIM 1024
#define BM 256
#define BN 256
#define BK 64
#define NT (K_DIM / BK)        // 16 K-tiles
#define AELEM (BM * BK)        // 16384 elems = 32 KB per operand-tile
// LDS: A slots 0..2 (3-deep), B slots 3..4 (2-deep) = 160 KB exactly

// ---------------- x: f32 -> bf16 (RNE), vectorized ----------------
__global__ void cvt_x_bf16(const float* __restrict__ x,
                           unsigned short* __restrict__ xb, int n8) {
    int i = blockIdx.x * blockDim.x + threadIdx.x;
    int stride = gridDim.x * blockDim.x;
    for (; i < n8; i += stride) {
        const float4* p = (const float4*)(x + (size_t)i * 8);
        float4 v0 = p[0], v1 = p[1];
        float vv[8] = {v0.x, v0.y, v0.z, v0.w, v1.x, v1.y, v1.z, v1.w};
        ushort8 o;
#pragma unroll
        for (int j = 0; j < 8; ++j) {
            uint32_t u = __builtin_bit_cast(uint32_t, vv[j]);
            u = u + 0x7FFFu + ((u >> 16) & 1u);   // round-to-nearest-even
            o[j] = (unsigned short)(u >> 16);
        }
        *(ushort8*)(xb + (size_t)i * 8) = o;
    }
}

// ------- W: binarize (exact reference semantics) + transpose to [N][K] -------
__global__ void bin_transpose_w(const float* __restrict__ W,
                                unsigned short* __restrict__ WbT) {
    __shared__ unsigned short t[64][68];
    int tj = blockIdx.x;                   // n tile
    int ti = blockIdx.y;                   // k tile
    int tid = threadIdx.x;
    int c4 = (tid & 15) * 4;
    int r0 = tid >> 4;
#pragma unroll
    for (int p = 0; p < 4; ++p) {
        int r = r0 + p * 16;
        float4 v = *(const float4*)(W + (size_t)(ti * 64 + r) * N_DIM + tj * 64 + c4);
        // reference: +1 iff (w+1)/2 > 0.5 (round-half-even at exactly 0.5 -> -1)
        t[r][c4 + 0] = ((v.x + 1.0f) * 0.5f > 0.5f) ? 0x3F80 : 0xBF80;
        t[r][c4 + 1] = ((v.y + 1.0f) * 0.5f > 0.5f) ? 0x3F80 : 0xBF80;
        t[r][c4 + 2] = ((v.z + 1.0f) * 0.5f > 0.5f) ? 0x3F80 : 0xBF80;
        t[r][c4 + 3] = ((v.w + 1.0f) * 0.5f > 0.5f) ? 0x3F80 : 0xBF80;
    }
    __syncthreads();
#pragma unroll
    for (int p = 0; p < 4; ++p) {
        int rn = r0 + p * 16;
        ushort4 o;
        o.x = t[c4 + 0][rn];
        o.y = t[c4 + 1][rn];
        o.z = t[c4 + 2][rn];
        o.w = t[c4 + 3][rn];
        *(ushort4*)(WbT + (size_t)(tj * 64 + rn) * K_DIM + ti * 64 + c4) = o;
    }
}

// ---------------- counted-vmcnt pipelined bf16 GEMM (32x32x16 MFMA) ----------------
__device__ __forceinline__ void gload16(const bf16_t* g, const bf16_t* l) {
    __builtin_amdgcn_global_load_lds(
        (const __attribute__((address_space(1))) void*)(g),
        (__attribute__((address_space(3))) void*)(l),
        16, 0, 0);
}

__global__ __launch_bounds__(512, 2) void bgemm(const bf16_t* __restrict__ A,
                                                const bf16_t* __restrict__ Bt,
                                                const float* __restrict__ bias,
                                                float* __restrict__ C) {
    __shared__ __align__(16) bf16_t lds[5 * AELEM];   // 160 KB: A x3 + B x2

    const int nwg = (M_DIM / BM) * (N_DIM / BN);   // 256, %8==0
    int bid = blockIdx.x;
    int swz = (bid & 7) * (nwg >> 3) + (bid >> 3); // XCD-aware, bijective
    int tile_n = swz & 3;                          // consecutive swz share A panel
    int tile_m = swz >> 2;
    int bm0 = tile_m * BM;
    int bn0 = tile_n * BN;

    int tid = threadIdx.x;
    int w = tid >> 6, l = tid & 63;    // 8 waves: 2(M) x 4(N)
    int wr = w >> 2, wc = w & 3;       // per-wave 128x64 output
    int l31 = l & 31, lh = l >> 5;

    // staging: linear LDS dest (lane-contiguous 16B); T2 swizzle via
    // pre-swizzled per-lane GLOBAL source chunk (both-sides rule)
    int srow = tid >> 3;                         // 0..63 within a 64-row call
    int schunk = (tid & 7) ^ (srow & 7);
    auto stageA = [&](int t, int c) {
        gload16(A + (size_t)(bm0 + c * 64 + srow) * K_DIM + t * BK + schunk * 8,
                lds + (t % 3) * AELEM + c * 4096 + tid * 8);
    };
    auto stageB = [&](int t, int c) {
        gload16(Bt + (size_t)(bn0 + c * 64 + srow) * K_DIM + t * BK + schunk * 8,
                lds + (3 + (t & 1)) * AELEM + c * 4096 + tid * 8);
    };

    f32x16 acc[4][2];
#pragma unroll
    for (int m = 0; m < 4; ++m)
#pragma unroll
        for (int n = 0; n < 2; ++n)
            acc[m][n] = (f32x16)(0.0f);

    // ---- prologue: stage A(0), B(0), A(1); retire A0+B0, keep A1 in flight ----
#pragma unroll
    for (int c = 0; c < 4; ++c) stageA(0, c);
#pragma unroll
    for (int c = 0; c < 4; ++c) stageB(0, c);
#pragma unroll
    for (int c = 0; c < 4; ++c) stageA(1, c);
    asm volatile("s_waitcnt vmcnt(4)" ::: "memory");
    __builtin_amdgcn_s_barrier();

    bf16x8 bfr[2][4];
    for (int t = 0; t < NT; ++t) {
        const bf16_t* Ab = lds + (t % 3) * AELEM;
        const bf16_t* Bb = lds + (3 + (t & 1)) * AELEM;

#pragma unroll
        for (int P = 0; P < 4; ++P) {
            // ---- ds-reads: A row-block P (4 x b128); phase 0 also B (8 x b128) ----
            bf16x8 afr[4];
            int arow = wr * 128 + P * 32 + l31;
#pragma unroll
            for (int ks = 0; ks < 4; ++ks)
                afr[ks] = *(const bf16x8*)(Ab + arow * BK
                                           + (((ks * 2 + lh) ^ (arow & 7)) * 8));
            if (P == 0) {
#pragma unroll
                for (int ns = 0; ns < 2; ++ns) {
                    int brow = wc * 64 + ns * 32 + l31;
#pragma unroll
                    for (int ks = 0; ks < 4; ++ks)
                        bfr[ns][ks] = *(const bf16x8*)(Bb + brow * BK
                                                       + (((ks * 2 + lh) ^ (brow & 7)) * 8));
                }
            }
            // ---- stage: phases 0-1 -> B(t+1); phases 2-3 -> A(t+2) ----
            if (P < 2) {
                if (t + 1 < NT) { stageB(t + 1, P * 2); stageB(t + 1, P * 2 + 1); }
            } else {
                if (t + 2 < NT) { stageA(t + 2, (P - 2) * 2); stageA(t + 2, (P - 2) * 2 + 1); }
            }
            if (P == 0) asm volatile("s_waitcnt lgkmcnt(8)" ::: "memory");
            __builtin_amdgcn_s_barrier();
            asm volatile("s_waitcnt lgkmcnt(0)" ::: "memory");
            __builtin_amdgcn_sched_barrier(0);
            __builtin_amdgcn_s_setprio(1);
#pragma unroll
            for (int ks = 0; ks < 4; ++ks)
#pragma unroll
                for (int ns = 0; ns < 2; ++ns)
                    acc[P][ns] = __builtin_amdgcn_mfma_f32_32x32x16_bf16(
                        afr[ks], bfr[ns][ks], acc[P][ns], 0, 0, 0);
            __builtin_amdgcn_s_setprio(0);
            if (P < 3) __builtin_amdgcn_s_barrier();
        }

        // ---- boundary: retire A(t+1)+B(t+1); A(t+2) stays in flight (T4) ----
        if (t + 1 < NT) {
            if (t + 2 < NT)
                asm volatile("s_waitcnt vmcnt(4)" ::: "memory");
            else
                asm volatile("s_waitcnt vmcnt(0)" ::: "memory");
            __builtin_amdgcn_s_barrier();
        }
    }

    // ---- epilogue: 32x32 C/D layout col=lane&31, row=(reg&3)+8*(reg>>2)+4*(lane>>5)
#pragma unroll
    for (int ns = 0; ns < 2; ++ns) {
        int col = bn0 + wc * 64 + ns * 32 + l31;
        float bv = bias[col];
#pragma unroll
        for (int P = 0; P < 4; ++P) {
            int rowbase = bm0 + wr * 128 + P * 32 + 4 * lh;
#pragma unroll
            for (int rg = 0; rg < 4; ++rg)
#pragma unroll
                for (int j = 0; j < 4; ++j)
                    C[(size_t)(rowbase + rg * 8 + j) * N_DIM + col]
                        = acc[P][ns][rg * 4 + j] + bv;
        }
    }
}

// ---------------- fallback (only if workspace too small) ----------------
__global__ void naive_bin_dense(const float* __restrict__ x,
                                const float* __restrict__ W,
                                const float* __restrict__ b,
                                float* __restrict__ out) {
    int col = blockIdx.x * 256 + threadIdx.x;
    int row = blockIdx.y;
    float acc = 0.0f;
    for (int k = 0; k < K_DIM; ++k) {
        float s = ((W[(size_t)k * N_DIM + col] + 1.0f) * 0.5f > 0.5f) ? 1.0f : -1.0f;
        acc += x[(size_t)row * K_DIM + k] * s;
    }
    out[(size_t)row * N_DIM + col] = acc + b[col];
}

extern "C" void kernel_launch(void* const* d_in, const int* in_sizes, int n_in,
                              void* d_out, int out_size, void* d_ws, size_t ws_size,
                              hipStream_t stream) {
    const float* x = (const float*)d_in[0];
    const float* W = (const float*)d_in[1];
    const float* b = (const float*)d_in[2];
    float* out = (float*)d_out;

    size_t xb_bytes = (size_t)M_DIM * K_DIM * sizeof(unsigned short);
    size_t wb_bytes = (size_t)K_DIM * N_DIM * sizeof(unsigned short);

    if (ws_size >= xb_bytes + wb_bytes) {
        unsigned short* xb = (unsigned short*)d_ws;
        unsigned short* wbt = (unsigned short*)((char*)d_ws + xb_bytes);
        hipLaunchKernelGGL(bin_transpose_w, dim3(N_DIM / 64, K_DIM / 64), dim3(256),
                           0, stream, W, wbt);
        hipLaunchKernelGGL(cvt_x_bf16, dim3(2048), dim3(256), 0, stream,
                           x, xb, (M_DIM * K_DIM) / 8);
        hipLaunchKernelGGL(bgemm, dim3((M_DIM / BM) * (N_DIM / BN)), dim3(512), 0, stream,
                           (const bf16_t*)xb, (const bf16_t*)wbt, b, out);
    } else {
        hipLaunchKernelGGL(naive_bin_dense, dim3(N_DIM / 256, M_DIM), dim3(256),
                           0, stream, x, W, b, out);
    }
}

// Round 6
// 61.769 us; speedup vs baseline: 1.0206x; 1.0206x over previous
//
#include <hip/hip_runtime.h>
#include <stdint.h>

typedef __bf16 bf16_t;
typedef __bf16 bf16x8 __attribute__((ext_vector_type(8)));
typedef float f32x4 __attribute__((ext_vector_type(4)));
typedef unsigned short ushort8 __attribute__((ext_vector_type(8)));

#define M_DIM 16384
#define N_DIM 1024
#define K_DIM 1024
#define BM 256
#define BN 256
#define BK 64
#define NT (K_DIM / BK)        // 16 K-tiles
#define AELEM (BM * BK)        // 16384 elems = 32 KB per operand-tile
// LDS: A slots 0..2 (3-deep), B slots 3..4 (2-deep) = 160 KB exactly

// ---------------- x: f32 -> bf16 (RNE), vectorized ----------------
__global__ void cvt_x_bf16(const float* __restrict__ x,
                           unsigned short* __restrict__ xb, int n8) {
    int i = blockIdx.x * blockDim.x + threadIdx.x;
    int stride = gridDim.x * blockDim.x;
    for (; i < n8; i += stride) {
        const float4* p = (const float4*)(x + (size_t)i * 8);
        float4 v0 = p[0], v1 = p[1];
        float vv[8] = {v0.x, v0.y, v0.z, v0.w, v1.x, v1.y, v1.z, v1.w};
        ushort8 o;
#pragma unroll
        for (int j = 0; j < 8; ++j) {
            uint32_t u = __builtin_bit_cast(uint32_t, vv[j]);
            u = u + 0x7FFFu + ((u >> 16) & 1u);   // round-to-nearest-even
            o[j] = (unsigned short)(u >> 16);
        }
        *(ushort8*)(xb + (size_t)i * 8) = o;
    }
}

// ------- W: binarize (exact reference semantics) + transpose to [N][K] -------
__global__ void bin_transpose_w(const float* __restrict__ W,
                                unsigned short* __restrict__ WbT) {
    __shared__ unsigned short t[64][68];
    int tj = blockIdx.x;                   // n tile
    int ti = blockIdx.y;                   // k tile
    int tid = threadIdx.x;
    int c4 = (tid & 15) * 4;
    int r0 = tid >> 4;
#pragma unroll
    for (int p = 0; p < 4; ++p) {
        int r = r0 + p * 16;
        float4 v = *(const float4*)(W + (size_t)(ti * 64 + r) * N_DIM + tj * 64 + c4);
        // reference: +1 iff (w+1)/2 > 0.5 (round-half-even at exactly 0.5 -> -1)
        t[r][c4 + 0] = ((v.x + 1.0f) * 0.5f > 0.5f) ? 0x3F80 : 0xBF80;
        t[r][c4 + 1] = ((v.y + 1.0f) * 0.5f > 0.5f) ? 0x3F80 : 0xBF80;
        t[r][c4 + 2] = ((v.z + 1.0f) * 0.5f > 0.5f) ? 0x3F80 : 0xBF80;
        t[r][c4 + 3] = ((v.w + 1.0f) * 0.5f > 0.5f) ? 0x3F80 : 0xBF80;
    }
    __syncthreads();
#pragma unroll
    for (int p = 0; p < 4; ++p) {
        int rn = r0 + p * 16;
        ushort4 o;
        o.x = t[c4 + 0][rn];
        o.y = t[c4 + 1][rn];
        o.z = t[c4 + 2][rn];
        o.w = t[c4 + 3][rn];
        *(ushort4*)(WbT + (size_t)(tj * 64 + rn) * K_DIM + ti * 64 + c4) = o;
    }
}

// ---------------- counted-vmcnt pipelined bf16 GEMM (16x16x32 MFMA) ----------------
__device__ __forceinline__ void gload16(const bf16_t* g, const bf16_t* l) {
    __builtin_amdgcn_global_load_lds(
        (const __attribute__((address_space(1))) void*)(g),
        (__attribute__((address_space(3))) void*)(l),
        16, 0, 0);
}

// one phase: 4 A ds_reads + 2 stage issues -> barrier -> 16 MFMA
#define PHASE_BODY(P, S0, S1)                                                   \
    {                                                                           \
        bf16x8 afr[2][2];                                                       \
        _Pragma("unroll") for (int i = 0; i < 2; ++i)                           \
            _Pragma("unroll") for (int k = 0; k < 2; ++k)                       \
                afr[i][k] = *(const bf16x8*)(Ab + (wr * 128 + ((P)*2 + i) * 16 + lr) * BK \
                                             + (((k * 4 + lk) ^ l7) * 8));      \
        S0; S1;                                                                 \
        __builtin_amdgcn_s_barrier();                                           \
        asm volatile("s_waitcnt lgkmcnt(0)" ::: "memory");                      \
        __builtin_amdgcn_sched_barrier(0);                                      \
        __builtin_amdgcn_s_setprio(1);                                          \
        _Pragma("unroll") for (int i = 0; i < 2; ++i)                           \
            _Pragma("unroll") for (int n = 0; n < 4; ++n)                       \
                _Pragma("unroll") for (int k = 0; k < 2; ++k)                   \
                    acc[(P)*2 + i][n] = __builtin_amdgcn_mfma_f32_16x16x32_bf16(\
                        afr[i][k], bfr[n][k], acc[(P)*2 + i][n], 0, 0, 0);      \
        __builtin_amdgcn_s_setprio(0);                                          \
    }

__global__ __launch_bounds__(512, 2) void bgemm(const bf16_t* __restrict__ A,
                                                const bf16_t* __restrict__ Bt,
                                                const float* __restrict__ bias,
                                                float* __restrict__ C) {
    __shared__ __align__(16) bf16_t lds[5 * AELEM];   // 160 KB: A x3 + B x2

    const int nwg = (M_DIM / BM) * (N_DIM / BN);   // 256, %8==0
    int bid = blockIdx.x;
    int swz = (bid & 7) * (nwg >> 3) + (bid >> 3); // XCD-aware, bijective
    int tile_n = swz & 3;                          // consecutive swz share A panel
    int tile_m = swz >> 2;
    int bm0 = tile_m * BM;
    int bn0 = tile_n * BN;

    int tid = threadIdx.x;
    int w = tid >> 6, l = tid & 63;    // 8 waves: 2(M) x 4(N)
    int wr = w >> 2, wc = w & 3;       // per-wave 128x64 output
    int lr = l & 15, lk = l >> 4, l7 = l & 7;

    // staging: linear LDS dest (lane-contiguous 16B); T2 swizzle via
    // pre-swizzled per-lane GLOBAL source chunk (both-sides rule)
    int srow = tid >> 3;                         // 0..63 within a 64-row call
    int schunk = (tid & 7) ^ (srow & 7);
    auto stageA1 = [&](int t, int c) {
        gload16(A + (size_t)(bm0 + c * 64 + srow) * K_DIM + t * BK + schunk * 8,
                lds + (t % 3) * AELEM + c * 4096 + tid * 8);
    };
    auto stageB1 = [&](int t, int c) {
        gload16(Bt + (size_t)(bn0 + c * 64 + srow) * K_DIM + t * BK + schunk * 8,
                lds + (3 + (t & 1)) * AELEM + c * 4096 + tid * 8);
    };

    f32x4 acc[8][4];
#pragma unroll
    for (int m = 0; m < 8; ++m)
#pragma unroll
        for (int n = 0; n < 4; ++n)
            acc[m][n] = (f32x4)(0.0f);

    // ---- prologue: stage A(0), B(0), A(1); retire A0+B0, keep A1 in flight ----
#pragma unroll
    for (int c = 0; c < 4; ++c) stageA1(0, c);
#pragma unroll
    for (int c = 0; c < 4; ++c) stageB1(0, c);
#pragma unroll
    for (int c = 0; c < 4; ++c) stageA1(1, c);
    asm volatile("s_waitcnt vmcnt(4)" ::: "memory");
    __builtin_amdgcn_s_barrier();

    for (int t = 0; t < NT; ++t) {
        const bf16_t* Ab = lds + (t % 3) * AELEM;
        const bf16_t* Bb = lds + (3 + (t & 1)) * AELEM;
        bool pfB = (t + 1) < NT;
        bool pfA = (t + 2) < NT;

        // B frags: loaded once in phase 0, register-resident for all 4 phases
        bf16x8 bfr[4][2];
#pragma unroll
        for (int n = 0; n < 4; ++n)
#pragma unroll
            for (int k = 0; k < 2; ++k)
                bfr[n][k] = *(const bf16x8*)(Bb + (wc * 64 + n * 16 + lr) * BK
                                             + (((k * 4 + lk) ^ l7) * 8));

        // phases 0-1 stage B(t+1); phases 2-3 stage A(t+2)  [T4: issue early]
        PHASE_BODY(0, if (pfB) stageB1(t + 1, 0), if (pfB) stageB1(t + 1, 1));
        __builtin_amdgcn_s_barrier();
        PHASE_BODY(1, if (pfB) stageB1(t + 1, 2), if (pfB) stageB1(t + 1, 3));
        __builtin_amdgcn_s_barrier();
        PHASE_BODY(2, if (pfA) stageA1(t + 2, 0), if (pfA) stageA1(t + 2, 1));
        __builtin_amdgcn_s_barrier();
        PHASE_BODY(3, if (pfA) stageA1(t + 2, 2), if (pfA) stageA1(t + 2, 3));

        // ---- boundary: retire A(t+1)+B(t+1); A(t+2) stays in flight (T4) ----
        if (t + 1 < NT) {
            if (t + 2 < NT)
                asm volatile("s_waitcnt vmcnt(4)" ::: "memory");
            else
                asm volatile("s_waitcnt vmcnt(0)" ::: "memory");
            __builtin_amdgcn_s_barrier();
        }
    }

    // ---- epilogue: C/D layout col = lane&15, row = (lane>>4)*4 + reg ----
#pragma unroll
    for (int n = 0; n < 4; ++n) {
        int col = bn0 + wc * 64 + n * 16 + lr;
        float bv = bias[col];
#pragma unroll
        for (int m = 0; m < 8; ++m) {
            int row0 = bm0 + wr * 128 + m * 16 + lk * 4;
#pragma unroll
            for (int j = 0; j < 4; ++j)
                C[(size_t)(row0 + j) * N_DIM + col] = acc[m][n][j] + bv;
        }
    }
}

// ---------------- fallback (only if workspace too small) ----------------
__global__ void naive_bin_dense(const float* __restrict__ x,
                                const float* __restrict__ W,
                                const float* __restrict__ b,
                                float* __restrict__ out) {
    int col = blockIdx.x * 256 + threadIdx.x;
    int row = blockIdx.y;
    float acc = 0.0f;
    for (int k = 0; k < K_DIM; ++k) {
        float s = ((W[(size_t)k * N_DIM + col] + 1.0f) * 0.5f > 0.5f) ? 1.0f : -1.0f;
        acc += x[(size_t)row * K_DIM + k] * s;
    }
    out[(size_t)row * N_DIM + col] = acc + b[col];
}

extern "C" void kernel_launch(void* const* d_in, const int* in_sizes, int n_in,
                              void* d_out, int out_size, void* d_ws, size_t ws_size,
                              hipStream_t stream) {
    const float* x = (const float*)d_in[0];
    const float* W = (const float*)d_in[1];
    const float* b = (const float*)d_in[2];
    float* out = (float*)d_out;

    size_t xb_bytes = (size_t)M_DIM * K_DIM * sizeof(unsigned short);
    size_t wb_bytes = (size_t)K_DIM * N_DIM * sizeof(unsigned short);

    if (ws_size >= xb_bytes + wb_bytes) {
        unsigned short* xb = (unsigned short*)d_ws;
        unsigned short* wbt = (unsigned short*)((char*)d_ws + xb_bytes);
        hipLaunchKernelGGL(bin_transpose_w, dim3(N_DIM / 64, K_DIM / 64), dim3(256),
                           0, stream, W, wbt);
        hipLaunchKernelGGL(cvt_x_bf16, dim3(2048), dim3(256), 0, stream,
                           x, xb, (M_DIM * K_DIM) / 8);
        hipLaunchKernelGGL(bgemm, dim3((M_DIM / BM) * (N_DIM / BN)), dim3(512), 0, stream,
                           (const bf16_t*)xb, (const bf16_t*)wbt, b, out);
    } else {
        hipLaunchKernelGGL(naive_bin_dense, dim3(N_DIM / 256, M_DIM), dim3(256),
                           0, stream, x, W, b, out);
    }
}